// Round 2
// baseline (401.289 us; speedup 1.0000x reference)
//
#include <hip/hip_runtime.h>

typedef unsigned short u16;
typedef unsigned int   u32;

// Problem constants
#define B_    8
#define CIN   256
#define H_    64
#define W_    64
#define HW_   4096
#define REL_  32
#define OUT_  256
#define G_    32
#define MID_  320
#define WOUT_ 288
#define EPS_  1e-5f

// ---------- bf16 helpers ----------
__device__ __forceinline__ float bflo(u32 u) { return __uint_as_float(u << 16); }
__device__ __forceinline__ float bfhi(u32 u) { return __uint_as_float(u & 0xffff0000u); }
__device__ __forceinline__ float b2f(u16 v)  { return __uint_as_float(((u32)v) << 16); }
__device__ __forceinline__ u16   f2bf(float f) {
    u32 u = __float_as_uint(f);
    u += 0x7fffu + ((u >> 16) & 1u);   // round-to-nearest-even
    return (u16)(u >> 16);
}
// dtype-agnostic scalar load (isf32 is wave-uniform)
__device__ __forceinline__ float ldv(const void* p, int i, int isf32) {
    return isf32 ? ((const float*)p)[i] : b2f(((const u16*)p)[i]);
}

// ---------- workspace layout (bytes) ----------
#define X1F_OFF   0u                        // fp32 [8][32][4096]  = 4 MiB
#define X2F_OFF   (4u*1024u*1024u)          // fp32 [8][32][4096]  = 4 MiB
#define X3H_OFF   (8u*1024u*1024u)          // bf16 [8][256][4096] = 16 MiB
#define PAR_OFF   (24u*1024u*1024u)
#define FLAG_OFF  (PAR_OFF + 0u)            // u32 dtype flag (1 = f32 inputs)
#define BIAS_OFF  (PAR_OFF + 64u)           // fp32 [320]
#define S1_OFF    (PAR_OFF + 1344u)         // fp32 [320]
#define T1_OFF    (PAR_OFF + 2624u)         // fp32 [320]
#define S2_OFF    (PAR_OFF + 3904u)         // fp32 [32]
#define T2_OFF    (PAR_OFF + 4032u)         // fp32 [32]
#define CB2_OFF   (PAR_OFF + 4160u)         // fp32 [288]
#define CW1T_OFF  (PAR_OFF + 5312u)         // bf16 [320][32]   20480 B
#define CW2C_OFF  (PAR_OFF + 25792u)        // bf16 [288][32]   18432 B
#define WT_OFF    (PAR_OFF + 44224u)        // bf16 [256][320]  163840 B

// =====================================================================
// Kernel 0: dtype detect + parameter prep (BN fold, transposes, casts).
// Grid: 64 blocks x 256. Block 0 does small params; all blocks fill Wt.
// =====================================================================
__global__ __launch_bounds__(256) void setup_k(
    const void* __restrict__ w1, const void* __restrict__ b1,
    const void* __restrict__ w2, const void* __restrict__ b2,
    const void* __restrict__ w3, const void* __restrict__ b3,
    const void* __restrict__ bn1g, const void* __restrict__ bn1b,
    const void* __restrict__ bn1m, const void* __restrict__ bn1v,
    const void* __restrict__ cw1,
    const void* __restrict__ bn2g, const void* __restrict__ bn2b,
    const void* __restrict__ bn2m, const void* __restrict__ bn2v,
    const void* __restrict__ cw2, const void* __restrict__ cb2,
    u32* __restrict__ flagws,
    u16* __restrict__ Wt, float* __restrict__ biasAll,
    float* __restrict__ s1, float* __restrict__ t1,
    u16* __restrict__ cw1t, float* __restrict__ s2, float* __restrict__ t2,
    u16* __restrict__ cw2c, float* __restrict__ cb2f)
{
    __shared__ int sflag;
    const int tid = threadIdx.x;

    // ---- dtype detection from bn1_v (uniform in [0.5,1.5]) ----
    // bf16 storage: every 16-bit half encodes a value in [0.5,1.5]
    //   -> bits in [0x3F00, 0x3FC0] (inclusive: harness rounding can hit 1.5).
    // f32 storage: low 16 bits are mantissa noise; P(16 in-window) ~ 1e-40.
    if (tid == 0) {
        const u32* p = (const u32*)bn1v;
        int allb = 1;
        #pragma unroll
        for (int i = 0; i < 16; ++i) {
            u32 lo = p[i] & 0xffffu;
            if (lo < 0x3F00u || lo > 0x3FC0u) allb = 0;
        }
        sflag = allb ? 0 : 1;          // 1 = f32 inputs
        if (blockIdx.x == 0) *flagws = (u32)sflag;
    }
    __syncthreads();
    const int isf32 = sflag;

    // ---- Wt[c][oc] transpose (all blocks) ----
    const int gtid = blockIdx.x * 256 + tid;
    for (int idx = gtid; idx < CIN * MID_; idx += 64 * 256) {
        int c = idx / MID_, oc = idx % MID_;
        float v;
        if (oc < 32)       v = ldv(w1, oc * CIN + c, isf32);
        else if (oc < 64)  v = ldv(w2, (oc - 32) * CIN + c, isf32);
        else               v = ldv(w3, (oc - 64) * CIN + c, isf32);
        Wt[idx] = f2bf(v);
    }

    if (blockIdx.x != 0) return;

    // biases + BN1 fold
    for (int oc = tid; oc < MID_; oc += 256) {
        float bb;
        if (oc < 32)       bb = ldv(b1, oc, isf32);
        else if (oc < 64)  bb = ldv(b2, oc - 32, isf32);
        else               bb = ldv(b3, oc - 64, isf32);
        biasAll[oc] = bb;
        float g = ldv(bn1g, oc, isf32), v = ldv(bn1v, oc, isf32);
        float m = ldv(bn1m, oc, isf32), be = ldv(bn1b, oc, isf32);
        float s = g * rsqrtf(v + EPS_);
        s1[oc] = s;
        t1[oc] = be - m * s;
    }
    // cw1t[c][g]
    for (int idx = tid; idx < MID_ * G_; idx += 256) {
        int c = idx >> 5, g = idx & 31;
        cw1t[idx] = f2bf(ldv(cw1, g * MID_ + c, isf32));
    }
    // BN2 fold
    for (int g = tid; g < G_; g += 256) {
        float gg = ldv(bn2g, g, isf32), v = ldv(bn2v, g, isf32);
        float m = ldv(bn2m, g, isf32), be = ldv(bn2b, g, isf32);
        float s = gg * rsqrtf(v + EPS_);
        s2[g] = s;
        t2[g] = be - m * s;
    }
    // cw2 canonical bf16 [288][32] + cb2 f32
    for (int idx = tid; idx < WOUT_ * G_; idx += 256)
        cw2c[idx] = f2bf(ldv(cw2, idx, isf32));
    for (int o = tid; o < WOUT_; o += 256)
        cb2f[o] = ldv(cb2, o, isf32);
}

// =====================================================================
// Kernel 1: conv_in — Y[320][4096] = W[320][256] * X[256][4096] per batch
// block = one (b,h) row (64 px), loops 5 oc-tiles of 64; x resident in LDS.
// Writes x1,x2 (fp32) and x3 (bf16) to workspace.
// =====================================================================
__global__ __launch_bounds__(256) void conv_in_k(
    const void* __restrict__ x, const u16* __restrict__ Wt,
    const float* __restrict__ biasAll, const u32* __restrict__ flagp,
    float* __restrict__ x1f, float* __restrict__ x2f, u16* __restrict__ x3h)
{
    __shared__ u16 xs[CIN * 64];     // 32 KiB  x tile, bf16 [c][px]
    __shared__ u16 wlds[64 * 64];    // 8 KiB   w chunk, bf16 [cc][oc]

    const int blk = blockIdx.x;
    const int b = blk >> 6, h = blk & 63;
    const int tid = threadIdx.x;
    const int isf32 = (int)*flagp;

    // stage x row tile: 256 ch x 64 px
    if (isf32) {
        const float* xg = (const float*)x;
        const int base = (b * 256) * 4096 + h * 64;
        for (int idx = tid; idx < 16384; idx += 256) {
            int c = idx >> 6, p = idx & 63;
            xs[idx] = f2bf(xg[base + c * 4096 + p]);
        }
    } else {
        const u32* xg = (const u32*)x;
        u32* xsw = (u32*)xs;
        const int base_w = (b * 256) * 2048 + h * 32;
        for (int idx = tid; idx < 8192; idx += 256) {
            int c = idx >> 5, p2 = idx & 31;
            xsw[idx] = xg[base_w + c * 2048 + p2];
        }
    }

    const int pxq = tid & 15;   // px = pxq*4 + j
    const int ocq = tid >> 4;   // oc = oc0 + ocq*4 + i

    for (int ot = 0; ot < 5; ++ot) {
        const int oc0 = ot * 64;
        float acc[4][4] = {};

        for (int ct = 0; ct < 4; ++ct) {
            const int c0 = ct * 64;
            __syncthreads();
            {   // stage w chunk: 64 c x 64 oc  (Wt layout [c][oc], contiguous oc)
                const u32* wg = (const u32*)Wt;
                u32* wldsw = (u32*)wlds;
                const int row_w0 = c0 * 160 + (oc0 >> 1);
                for (int idx = tid; idx < 2048; idx += 256) {
                    int cc = idx >> 5, o2 = idx & 31;
                    wldsw[idx] = wg[row_w0 + cc * 160 + o2];
                }
            }
            __syncthreads();

            #pragma unroll 8
            for (int cc = 0; cc < 64; ++cc) {
                const int c = c0 + cc;
                uint2 xu = *(const uint2*)&xs[c * 64 + pxq * 4];
                uint2 wu = *(const uint2*)&wlds[cc * 64 + ocq * 4];
                float xv0 = bflo(xu.x), xv1 = bfhi(xu.x);
                float xv2 = bflo(xu.y), xv3 = bfhi(xu.y);
                float wv0 = bflo(wu.x), wv1 = bfhi(wu.x);
                float wv2 = bflo(wu.y), wv3 = bfhi(wu.y);
                acc[0][0] += wv0 * xv0; acc[0][1] += wv0 * xv1;
                acc[0][2] += wv0 * xv2; acc[0][3] += wv0 * xv3;
                acc[1][0] += wv1 * xv0; acc[1][1] += wv1 * xv1;
                acc[1][2] += wv1 * xv2; acc[1][3] += wv1 * xv3;
                acc[2][0] += wv2 * xv0; acc[2][1] += wv2 * xv1;
                acc[2][2] += wv2 * xv2; acc[2][3] += wv2 * xv3;
                acc[3][0] += wv3 * xv0; acc[3][1] += wv3 * xv1;
                acc[3][2] += wv3 * xv2; acc[3][3] += wv3 * xv3;
            }
        }

        // store this oc-tile
        const int hw = (h << 6) + pxq * 4;
        #pragma unroll
        for (int i = 0; i < 4; ++i) {
            int oc = oc0 + ocq * 4 + i;
            float bs = biasAll[oc];
            float v0 = acc[i][0] + bs, v1 = acc[i][1] + bs;
            float v2 = acc[i][2] + bs, v3 = acc[i][3] + bs;
            if (ot == 0) {
                float4 v = make_float4(v0, v1, v2, v3);
                if (oc < 32) *(float4*)&x1f[(((b << 5) + oc) << 12) + hw] = v;
                else         *(float4*)&x2f[(((b << 5) + (oc - 32)) << 12) + hw] = v;
            } else {
                int oc3 = oc - 64;
                ushort4 hv;
                hv.x = f2bf(v0); hv.y = f2bf(v1); hv.z = f2bf(v2); hv.w = f2bf(v3);
                *(ushort4*)&x3h[(((b << 8) + oc3) << 12) + hw] = hv;
            }
        }
    }
}

// =====================================================================
// Kernel 2: fused weight-gen (unfold+BN1+ReLU+cw1+BN2+ReLU+cw2) + local
// 3x3 grouped conv.  One block per (b,h) row, 256 threads, 64000 B LDS.
// =====================================================================
__global__ __launch_bounds__(256) void fused_k(
    const float* __restrict__ x1f, const float* __restrict__ x2f,
    const u16* __restrict__ x3h,
    const float* __restrict__ s1g, const float* __restrict__ t1g,
    const u16* __restrict__ cw1tg,
    const float* __restrict__ s2g, const float* __restrict__ t2g,
    const u16* __restrict__ cw2g, const float* __restrict__ cb2g,
    const u32* __restrict__ flagp, void* __restrict__ outv)
{
    __shared__ __align__(16) unsigned char smem[64000];
    // phase A/B region (union):
    float* x1row  = (float*)(smem);           // [32][64]      8192 B
    float* x2slab = (float*)(smem + 8192);    // [32][3][64]  24576 B
    float* s1     = (float*)(smem + 32768);   // [320]         1280 B
    float* t1     = (float*)(smem + 34048);   // [320]         1280 B
    u16*   cw1t   = (u16*)  (smem + 35328);   // [320][32]    20480 B -> 55808
    // phase D/E region (aliases A/B region):
    u16*   wloc   = (u16*)  (smem);           // [288][64]    36864 B
    u16*   cw2s   = (u16*)  (smem + 36864);   // [288][32]    18432 B -> 55296
    // persistent:
    float* aA     = (float*)(smem + 55808);   // [32][64]      8192 B -> 64000

    const int blk = blockIdx.x;
    const int b = blk >> 6, h = blk & 63;
    const int tid = threadIdx.x;
    const int px = tid & 63;
    const int isf32 = (int)*flagp;

    // ---- Phase A: stage ----
    for (int idx = tid; idx < 2048; idx += 256) {     // x1 row
        int c = idx >> 6, p = idx & 63;
        x1row[idx] = x1f[(((b << 5) + c) << 12) + (h << 6) + p];
    }
    for (int idx = tid; idx < 6144; idx += 256) {     // x2 3-row slab, reflect rows
        int r = idx / 192, rem = idx - r * 192;
        int i3 = rem >> 6, p = rem & 63;
        int hr = h + i3 - 1;
        hr = (hr < 0) ? 1 : ((hr > 63) ? 62 : hr);
        x2slab[idx] = x2f[(((b << 5) + r) << 12) + (hr << 6) + p];
    }
    for (int c = tid; c < MID_; c += 256) { s1[c] = s1g[c]; t1[c] = t1g[c]; }
    {
        const u32* src = (const u32*)cw1tg;
        u32* dst = (u32*)cw1t;
        for (int idx = tid; idx < 5120; idx += 256) dst[idx] = src[idx];
    }
    __syncthreads();

    // ---- Phase B: h2 = cw1 * relu(bn1(mid)), then bn2+relu -> aA ----
    {
        const int g0 = (tid >> 6) * 8;    // 8 contiguous groups per thread
        float acc8[8] = {};

        // x1 part: channels 0..31
        #pragma unroll 4
        for (int c = 0; c < 32; ++c) {
            float m = s1[c] * x1row[c * 64 + px] + t1[c];
            m = fmaxf(m, 0.f);
            uint4 wu = *(const uint4*)&cw1t[c * 32 + g0];
            acc8[0] += bflo(wu.x) * m; acc8[1] += bfhi(wu.x) * m;
            acc8[2] += bflo(wu.y) * m; acc8[3] += bfhi(wu.y) * m;
            acc8[4] += bflo(wu.z) * m; acc8[5] += bfhi(wu.z) * m;
            acc8[6] += bflo(wu.w) * m; acc8[7] += bfhi(wu.w) * m;
        }
        // x2 unfold part: channels 32 + r*9 + i3*3 + j3
        int pxo[3];
        pxo[0] = (px == 0) ? 1 : px - 1;
        pxo[1] = px;
        pxo[2] = (px == 63) ? 62 : px + 1;
        for (int r = 0; r < 32; ++r) {
            const int rbase = r * 192;
            #pragma unroll
            for (int i3 = 0; i3 < 3; ++i3) {
                const int rowb = rbase + i3 * 64;
                #pragma unroll
                for (int j3 = 0; j3 < 3; ++j3) {
                    const int c = 32 + r * 9 + i3 * 3 + j3;
                    float m = s1[c] * x2slab[rowb + pxo[j3]] + t1[c];
                    m = fmaxf(m, 0.f);
                    uint4 wu = *(const uint4*)&cw1t[c * 32 + g0];
                    acc8[0] += bflo(wu.x) * m; acc8[1] += bfhi(wu.x) * m;
                    acc8[2] += bflo(wu.y) * m; acc8[3] += bfhi(wu.y) * m;
                    acc8[4] += bflo(wu.z) * m; acc8[5] += bfhi(wu.z) * m;
                    acc8[6] += bflo(wu.w) * m; acc8[7] += bfhi(wu.w) * m;
                }
            }
        }
        // bn2 + relu
        #pragma unroll
        for (int j = 0; j < 8; ++j) {
            int g = g0 + j;
            float a = s2g[g] * acc8[j] + t2g[g];
            aA[g * 64 + px] = fmaxf(a, 0.f);
        }
    }
    __syncthreads();   // aA complete; A/B region now dead

    // ---- Phase D: stage cw2, compute wloc = cw2 * aA + cb2 ----
    {
        const u32* src = (const u32*)cw2g;
        u32* dst = (u32*)cw2s;
        for (int idx = tid; idx < 4608; idx += 256) dst[idx] = src[idx];
    }
    __syncthreads();
    {
        float areg[32];
        #pragma unroll
        for (int g = 0; g < 32; ++g) areg[g] = aA[g * 64 + px];
        const int og = tid >> 6;
        for (int o = og; o < WOUT_; o += 4) {
            float acc = cb2g[o];
            const uint4* row = (const uint4*)&cw2s[o * 32];
            #pragma unroll
            for (int q = 0; q < 4; ++q) {
                uint4 u = row[q];
                acc += bflo(u.x) * areg[q * 8 + 0] + bfhi(u.x) * areg[q * 8 + 1]
                     + bflo(u.y) * areg[q * 8 + 2] + bfhi(u.y) * areg[q * 8 + 3]
                     + bflo(u.z) * areg[q * 8 + 4] + bfhi(u.z) * areg[q * 8 + 5]
                     + bflo(u.w) * areg[q * 8 + 6] + bfhi(u.w) * areg[q * 8 + 7];
            }
            wloc[o * 64 + px] = f2bf(acc);
        }
    }
    __syncthreads();

    // ---- Phase E: local 3x3 grouped conv (zero pad) ----
    {
        const int gbase = (tid >> 6) * 8;
        for (int g = gbase; g < gbase + 8; ++g) {
            float wvf[9];
            #pragma unroll
            for (int k = 0; k < 9; ++k) wvf[k] = b2f(wloc[(g * 9 + k) * 64 + px]);
            #pragma unroll
            for (int s = 0; s < 8; ++s) {
                const int oc = g * 8 + s;
                const u16* x3b = x3h + (((b << 8) + oc) << 12);
                float acc = 0.f;
                #pragma unroll
                for (int i3 = 0; i3 < 3; ++i3) {
                    int hr = h + i3 - 1;
                    if (hr < 0 || hr > 63) continue;
                    const u16* rowp = x3b + (hr << 6);
                    #pragma unroll
                    for (int j3 = 0; j3 < 3; ++j3) {
                        int wc = px + j3 - 1;
                        if (wc < 0 || wc > 63) continue;
                        acc += wvf[i3 * 3 + j3] * b2f(rowp[wc]);
                    }
                }
                const int oidx = (((b << 8) + oc) << 12) + (h << 6) + px;
                if (isf32) ((float*)outv)[oidx] = acc;
                else       ((u16*)outv)[oidx] = f2bf(acc);
            }
        }
    }
}

// =====================================================================
extern "C" void kernel_launch(void* const* d_in, const int* in_sizes, int n_in,
                              void* d_out, int out_size, void* d_ws, size_t ws_size,
                              hipStream_t stream) {
    (void)in_sizes; (void)n_in; (void)out_size; (void)ws_size;
    char* ws = (char*)d_ws;
    float* x1f    = (float*)(ws + X1F_OFF);
    float* x2f    = (float*)(ws + X2F_OFF);
    u16*   x3h    = (u16*)  (ws + X3H_OFF);
    u32*   flagws = (u32*)  (ws + FLAG_OFF);
    float* biasAll= (float*)(ws + BIAS_OFF);
    float* s1     = (float*)(ws + S1_OFF);
    float* t1     = (float*)(ws + T1_OFF);
    float* s2     = (float*)(ws + S2_OFF);
    float* t2     = (float*)(ws + T2_OFF);
    float* cb2f   = (float*)(ws + CB2_OFF);
    u16*   cw1t   = (u16*)  (ws + CW1T_OFF);
    u16*   cw2c   = (u16*)  (ws + CW2C_OFF);
    u16*   Wt     = (u16*)  (ws + WT_OFF);

    hipLaunchKernelGGL(setup_k, dim3(64), dim3(256), 0, stream,
                       d_in[1], d_in[2], d_in[3], d_in[4], d_in[5], d_in[6],
                       d_in[7], d_in[8], d_in[9], d_in[10], d_in[11],
                       d_in[12], d_in[13], d_in[14], d_in[15], d_in[16], d_in[17],
                       flagws, Wt, biasAll, s1, t1, cw1t, s2, t2, cw2c, cb2f);
    hipLaunchKernelGGL(conv_in_k, dim3(B_ * H_), dim3(256), 0, stream,
                       d_in[0], Wt, biasAll, flagws, x1f, x2f, x3h);
    hipLaunchKernelGGL(fused_k, dim3(B_ * H_), dim3(256), 0, stream,
                       x1f, x2f, x3h, s1, t1, cw1t, s2, t2, cw2c, cb2f,
                       flagws, (u16*)d_out);
}

// Round 3
// 215.908 us; speedup vs baseline: 1.8586x; 1.8586x over previous
//
#include <hip/hip_runtime.h>

typedef unsigned short u16;
typedef unsigned int   u32;

#define B_    8
#define CIN   256
#define G_    32
#define MID_  320
#define WOUT_ 288
#define EPS_  1e-5f

typedef __attribute__((ext_vector_type(8))) short bf16x8;
typedef __attribute__((ext_vector_type(4))) float f32x4;

__device__ __forceinline__ float b2f(u16 v)  { return __uint_as_float(((u32)v) << 16); }
__device__ __forceinline__ u16   f2bf(float f) {
    u32 u = __float_as_uint(f);
    u += 0x7fffu + ((u >> 16) & 1u);
    return (u16)(u >> 16);
}
__device__ __forceinline__ float ldv(const void* p, int i, int isf32) {
    return isf32 ? ((const float*)p)[i] : b2f(((const u16*)p)[i]);
}

// ---------------- workspace layout (bytes) ----------------
#define OFF_Y     0u               // bf16 [8][320][4096]  20.97 MB
#define OFF_XT    (22u<<20)        // bf16 [8][4096][256]  16.78 MB (dead after conv_k)
#define OFF_WLOC  (22u<<20)        // bf16 [8][288][4096]  18.87 MB (aliases XT)
#define OFF_AAT   (41u<<20)        // bf16 [8][4096][32]   2.10 MB
#define PAR_OFF   (44u<<20)
#define FLAG_OFF  (PAR_OFF + 0u)
#define BIAS_OFF  (PAR_OFF + 64u)      // f32 [320]
#define S1_OFF    (PAR_OFF + 1344u)    // f32 [320]
#define T1_OFF    (PAR_OFF + 2624u)    // f32 [320]
#define S2_OFF    (PAR_OFF + 3904u)    // f32 [32]
#define T2_OFF    (PAR_OFF + 4032u)    // f32 [32]
#define CB2_OFF   (PAR_OFF + 4160u)    // f32 [288]
#define CW1_OFF   (PAR_OFF + 5312u)    // bf16 [32][320]
#define CW2_OFF   (PAR_OFF + 25792u)   // bf16 [288][32]
#define WC_OFF    (PAR_OFF + 44224u)   // bf16 [320][256]

// =====================================================================
// setup: dtype detect, BN folds, canonical bf16 weights
// =====================================================================
__global__ __launch_bounds__(256) void setup_k(
    const void* __restrict__ w1, const void* __restrict__ b1,
    const void* __restrict__ w2, const void* __restrict__ b2,
    const void* __restrict__ w3, const void* __restrict__ b3,
    const void* __restrict__ bn1g, const void* __restrict__ bn1b,
    const void* __restrict__ bn1m, const void* __restrict__ bn1v,
    const void* __restrict__ cw1,
    const void* __restrict__ bn2g, const void* __restrict__ bn2b,
    const void* __restrict__ bn2m, const void* __restrict__ bn2v,
    const void* __restrict__ cw2, const void* __restrict__ cb2,
    u32* __restrict__ flagws, u16* __restrict__ Wc, float* __restrict__ biasAll,
    float* __restrict__ s1, float* __restrict__ t1,
    u16* __restrict__ cw1c, float* __restrict__ s2, float* __restrict__ t2,
    u16* __restrict__ cw2c, float* __restrict__ cb2f)
{
    __shared__ int sflag;
    const int tid = threadIdx.x;
    if (tid == 0) {
        const u32* p = (const u32*)bn1v;
        int allb = 1;
        #pragma unroll
        for (int i = 0; i < 16; ++i) {
            u32 lo = p[i] & 0xffffu;
            if (lo < 0x3F00u || lo > 0x3FC0u) allb = 0;
        }
        sflag = allb ? 0 : 1;
        if (blockIdx.x == 0) *flagws = (u32)sflag;
    }
    __syncthreads();
    const int isf32 = sflag;

    // Wc[oc][c] = concat rows of w1,w2,w3 (bf16)
    const int gtid = blockIdx.x * 256 + tid;
    for (int idx = gtid; idx < MID_ * CIN; idx += 64 * 256) {
        int oc = idx >> 8, c = idx & 255;
        float v;
        if (oc < 32)       v = ldv(w1, oc * CIN + c, isf32);
        else if (oc < 64)  v = ldv(w2, (oc - 32) * CIN + c, isf32);
        else               v = ldv(w3, (oc - 64) * CIN + c, isf32);
        Wc[idx] = f2bf(v);
    }
    if (blockIdx.x != 0) return;

    for (int oc = tid; oc < MID_; oc += 256) {
        float bb;
        if (oc < 32)       bb = ldv(b1, oc, isf32);
        else if (oc < 64)  bb = ldv(b2, oc - 32, isf32);
        else               bb = ldv(b3, oc - 64, isf32);
        biasAll[oc] = bb;
        float g = ldv(bn1g, oc, isf32), v = ldv(bn1v, oc, isf32);
        float m = ldv(bn1m, oc, isf32), be = ldv(bn1b, oc, isf32);
        float s = g * rsqrtf(v + EPS_);
        s1[oc] = s;
        t1[oc] = be - m * s;
    }
    for (int idx = tid; idx < G_ * MID_; idx += 256)   // cw1c [32][320] direct
        cw1c[idx] = f2bf(ldv(cw1, idx, isf32));
    for (int g = tid; g < G_; g += 256) {
        float gg = ldv(bn2g, g, isf32), v = ldv(bn2v, g, isf32);
        float m = ldv(bn2m, g, isf32), be = ldv(bn2b, g, isf32);
        float s = gg * rsqrtf(v + EPS_);
        s2[g] = s;
        t2[g] = be - m * s;
    }
    for (int idx = tid; idx < WOUT_ * G_; idx += 256)  // cw2c [288][32] direct
        cw2c[idx] = f2bf(ldv(cw2, idx, isf32));
    for (int o = tid; o < WOUT_; o += 256)
        cb2f[o] = ldv(cb2, o, isf32);
}

// =====================================================================
// transpose: x[b][c][hw] -> Xt[b][hw][c] (bf16, with dtype cvt)
// =====================================================================
__global__ __launch_bounds__(256) void transpose_k(
    const void* __restrict__ x, const u32* __restrict__ flagp, u16* __restrict__ Xt)
{
    __shared__ u16 tile[64 * 68];
    const int pt = blockIdx.x, ct = blockIdx.y, b = blockIdx.z;
    const int c0 = ct * 64, hw0 = pt * 64;
    const int t = threadIdx.x;
    const int isf32 = (int)*flagp;

    if (isf32) {
        const float* xf = (const float*)x;
        for (int p = 0; p < 8; ++p) {
            int idx = t + 256 * p;
            int i = idx >> 5, j2 = idx & 31;
            float2 v = *(const float2*)&xf[((b * 256 + c0 + i) * 4096) + hw0 + 2 * j2];
            u32 pk = (u32)f2bf(v.x) | ((u32)f2bf(v.y) << 16);
            *(u32*)&tile[i * 68 + 2 * j2] = pk;
        }
    } else {
        const u32* xh = (const u32*)x;
        for (int p = 0; p < 8; ++p) {
            int idx = t + 256 * p;
            int i = idx >> 5, j2 = idx & 31;
            u32 pk = xh[(((b * 256 + c0 + i) * 4096) + hw0) / 2 + j2];
            *(u32*)&tile[i * 68 + 2 * j2] = pk;
        }
    }
    __syncthreads();
    u32* Xtw = (u32*)Xt;
    for (int p = 0; p < 8; ++p) {
        int idx = t + 256 * p;
        int j = idx >> 5, iw = idx & 31;
        u32 pk = (u32)tile[(2 * iw) * 68 + j] | ((u32)tile[(2 * iw + 1) * 68 + j] << 16);
        Xtw[(((b * 4096) + hw0 + j) * 256 + c0) / 2 + iw] = pk;
    }
}

// =====================================================================
// conv_k (MFMA): y[b][320][4096] = Wc[320][256] * X + bias  (bf16 out)
// block: 64 oc x 256 px, 4 waves; A resident, B per-k-step.
// =====================================================================
__global__ __launch_bounds__(256) void conv_k(
    const u16* __restrict__ Wc, const u16* __restrict__ Xt,
    const float* __restrict__ biasAll, u16* __restrict__ y)
{
    __shared__ u16 As[64 * 264];   // [oc][c] pad 264
    __shared__ u16 Bs[256 * 32];   // [px][c-chunk]
    const int pt = blockIdx.x, mt5 = blockIdx.y, b = blockIdx.z;
    const int oc0 = mt5 * 64, pxb = pt * 256;
    const int t = threadIdx.x;
    const int lane = t & 63, wv = t >> 6;
    const int l16 = lane & 15, quad = lane >> 4;

    {   // stage full-depth A
        const uint4* wg = (const uint4*)Wc;     // row = 32 uint4
        for (int p = 0; p < 8; ++p) {
            int idx = t + 256 * p;
            int row = idx >> 5, ch = idx & 31;
            uint4 v = wg[(oc0 + row) * 32 + ch];
            *(uint4*)&As[row * 264 + ch * 8] = v;
        }
    }
    f32x4 acc[4][4];
    #pragma unroll
    for (int i = 0; i < 4; ++i)
        #pragma unroll
        for (int j = 0; j < 4; ++j) acc[i][j] = (f32x4){0.f, 0.f, 0.f, 0.f};

    for (int ks = 0; ks < 8; ++ks) {
        const int c0 = ks * 32;
        __syncthreads();
        {   // stage B: 256 px x 32 c
            const uint4* xg = (const uint4*)Xt;  // row = 32 uint4
            for (int p = 0; p < 4; ++p) {
                int idx = t + 256 * p;
                int px = idx >> 2, ch = idx & 3;
                uint4 v = xg[((b * 4096) + pxb + px) * 32 + ks * 4 + ch];
                *(uint4*)&Bs[px * 32 + ch * 8] = v;
            }
        }
        __syncthreads();
        bf16x8 af[4], bfr[4];
        #pragma unroll
        for (int mt = 0; mt < 4; ++mt)
            af[mt] = *(const bf16x8*)&As[(mt * 16 + l16) * 264 + c0 + quad * 8];
        #pragma unroll
        for (int nt = 0; nt < 4; ++nt)
            bfr[nt] = *(const bf16x8*)&Bs[(wv * 64 + nt * 16 + l16) * 32 + quad * 8];
        #pragma unroll
        for (int mt = 0; mt < 4; ++mt)
            #pragma unroll
            for (int nt = 0; nt < 4; ++nt)
                acc[mt][nt] = __builtin_amdgcn_mfma_f32_16x16x32_bf16(af[mt], bfr[nt], acc[mt][nt], 0, 0, 0);
    }
    // epilogue: bias + bf16 store
    float bias_r[4][4];
    #pragma unroll
    for (int mt = 0; mt < 4; ++mt)
        #pragma unroll
        for (int r = 0; r < 4; ++r)
            bias_r[mt][r] = biasAll[oc0 + mt * 16 + quad * 4 + r];
    #pragma unroll
    for (int mt = 0; mt < 4; ++mt) {
        int oc = oc0 + mt * 16 + quad * 4;
        #pragma unroll
        for (int nt = 0; nt < 4; ++nt) {
            int px = pxb + wv * 64 + nt * 16 + l16;
            #pragma unroll
            for (int r = 0; r < 4; ++r)
                y[((b * 320) + oc + r) * 4096 + px] = f2bf(acc[mt][nt][r] + bias_r[mt][r]);
        }
    }
}

// =====================================================================
// wgen1_k (MFMA): aAt[b][hw][32] = relu(bn2(cw1 . relu(bn1(mid))))
// C[px][g] orientation: A = midT (built in LDS), B = cw1 rows. One h-row/block.
// =====================================================================
__global__ __launch_bounds__(256) void wgen1_k(
    const u16* __restrict__ y, const u16* __restrict__ cw1c,
    const float* __restrict__ s1g, const float* __restrict__ t1g,
    const float* __restrict__ s2g, const float* __restrict__ t2g,
    u16* __restrict__ aAt)
{
    __shared__ u16 midT[64 * 40];        // [px][k-chunk] pad 40
    __shared__ u16 x2slab[32 * 3 * 64];  // [r][row][w]
    __shared__ u16 cw1s[32 * 328];       // [g][k] pad 328
    __shared__ float s1s[320], t1s[320], s2s[32], t2s[32];
    const int h = blockIdx.x, b = blockIdx.y;
    const int t = threadIdx.x;
    const int lane = t & 63, wv = t >> 6;
    const int l16 = lane & 15, quad = lane >> 4;
    const int hw0 = h * 64;

    {   // stage cw1: 32 g x 40 uint4
        const uint4* g4 = (const uint4*)cw1c;
        int g = t >> 3, l = t & 7;
        for (int q = 0; q < 5; ++q) {
            int ch = l + 8 * q;
            uint4 v = g4[g * 40 + ch];
            *(uint4*)&cw1s[g * 328 + ch * 8] = v;
        }
    }
    {   // stage x2 slab (reflect rows): r = t>>3, 96 u32 words per r
        const u32* yw = (const u32*)y;
        int r = t >> 3, l = t & 7;
        for (int q = 0; q < 12; ++q) {
            int wdx = l + 8 * q;
            int row = wdx >> 5, pw = wdx & 31;
            int hr = h + row - 1; hr = hr < 0 ? 1 : (hr > 63 ? 62 : hr);
            u32 v = yw[(((b * 320) + 32 + r) * 4096 + hr * 64) / 2 + pw];
            *(u32*)&x2slab[(r * 3 + row) * 64 + pw * 2] = v;
        }
    }
    for (int i = t; i < 320; i += 256) { s1s[i] = s1g[i]; t1s[i] = t1g[i]; }
    if (t < 32) { s2s[t] = s2g[t]; t2s[t] = t2g[t]; }
    __syncthreads();

    const int px = t & 63, oh = t >> 6;    // build: 1 oct of 8 k per thread
    const int w = px;
    const int wm = (w == 0) ? 1 : w - 1;
    const int wp = (w == 63) ? 62 : w + 1;

    f32x4 acc0 = {0.f,0.f,0.f,0.f}, acc1 = {0.f,0.f,0.f,0.f};

    for (int ks = 0; ks < 10; ++ks) {
        const int k0 = ks * 32;
        const int kb = k0 + oh * 8;
        u16 hv[8];
        if (kb < 32) {          // x1 channels (wave-uniform branch: only ks==0)
            #pragma unroll
            for (int j = 0; j < 8; ++j) {
                int k = kb + j;
                float v = b2f(y[((b * 320) + k) * 4096 + hw0 + px]);
                hv[j] = f2bf(fmaxf(s1s[k] * v + t1s[k], 0.f));
            }
        } else {                // unfold(x2) channels
            #pragma unroll
            for (int j = 0; j < 8; ++j) {
                int k = kb + j;
                int kk = k - 32;
                int r = (kk * 7282) >> 16;       // kk/9
                int tt = kk - 9 * r;
                int i3 = (tt * 11) >> 5;         // tt/3
                int j3 = tt - 3 * i3;
                int wj = (j3 == 0) ? wm : ((j3 == 1) ? w : wp);
                float v = b2f(x2slab[(r * 3 + i3) * 64 + wj]);
                hv[j] = f2bf(fmaxf(s1s[k] * v + t1s[k], 0.f));
            }
        }
        __syncthreads();   // prev MFMA reads of midT done
        {
            u32 pk0 = (u32)hv[0] | ((u32)hv[1] << 16);
            u32 pk1 = (u32)hv[2] | ((u32)hv[3] << 16);
            u32 pk2 = (u32)hv[4] | ((u32)hv[5] << 16);
            u32 pk3 = (u32)hv[6] | ((u32)hv[7] << 16);
            uint4 pk = make_uint4(pk0, pk1, pk2, pk3);
            *(uint4*)&midT[px * 40 + oh * 8] = pk;
        }
        __syncthreads();
        bf16x8 af  = *(const bf16x8*)&midT[(wv * 16 + l16) * 40 + quad * 8];
        bf16x8 bf0 = *(const bf16x8*)&cw1s[l16 * 328 + k0 + quad * 8];
        bf16x8 bf1 = *(const bf16x8*)&cw1s[(16 + l16) * 328 + k0 + quad * 8];
        acc0 = __builtin_amdgcn_mfma_f32_16x16x32_bf16(af, bf0, acc0, 0, 0, 0);
        acc1 = __builtin_amdgcn_mfma_f32_16x16x32_bf16(af, bf1, acc1, 0, 0, 0);
    }
    // epilogue: bn2 + relu -> aAt[b][hw][g]
    #pragma unroll
    for (int nt = 0; nt < 2; ++nt) {
        int g = l16 + nt * 16;
        float sg = s2s[g], tg = t2s[g];
        const f32x4& aa = nt ? acc1 : acc0;
        #pragma unroll
        for (int r = 0; r < 4; ++r) {
            int pxl = wv * 16 + quad * 4 + r;
            float a = fmaxf(sg * aa[r] + tg, 0.f);
            aAt[((b * 4096) + hw0 + pxl) * 32 + g] = f2bf(a);
        }
    }
}

// =====================================================================
// wgen2_k (MFMA, K=32): wloc[b][288][4096] = cw2 . aA + cb2 (bf16)
// C[px][o] orientation; LDS transpose for coalesced [o][px] stores.
// =====================================================================
__global__ __launch_bounds__(256) void wgen2_k(
    const u16* __restrict__ aAt, const u16* __restrict__ cw2c,
    const float* __restrict__ cb2f, u16* __restrict__ wloc)
{
    __shared__ u16 aAts[64 * 40];    // [px][g] pad 40
    __shared__ u16 cw2s[288 * 40];   // [o][g] pad 40
    __shared__ u16 wlT[64 * 40];     // [px][o-chunk] pad 40
    __shared__ float cb2s[288];
    const int h = blockIdx.x, b = blockIdx.y;
    const int hw0 = h * 64;
    const int t = threadIdx.x;
    const int lane = t & 63, wv = t >> 6;
    const int l16 = lane & 15, quad = lane >> 4;

    {   // stage aAt tile: 64 px x 4 uint4
        int px = t >> 2, ch = t & 3;
        uint4 v = *(const uint4*)&aAt[((b * 4096) + hw0 + px) * 32 + ch * 8];
        *(uint4*)&aAts[px * 40 + ch * 8] = v;
    }
    {   // stage cw2: 288 x 4 uint4
        const uint4* g4 = (const uint4*)cw2c;
        for (int idx = t; idx < 1152; idx += 256) {
            int o = idx >> 2, ch = idx & 3;
            uint4 v = g4[o * 4 + ch];
            *(uint4*)&cw2s[o * 40 + ch * 8] = v;
        }
        for (int i = t; i < 288; i += 256) cb2s[i] = cb2f[i];
    }
    __syncthreads();

    bf16x8 af = *(const bf16x8*)&aAts[(wv * 16 + l16) * 40 + quad * 8];
    u32* wlw = (u32*)wloc;

    for (int nc = 0; nc < 9; ++nc) {
        f32x4 a0 = {0.f,0.f,0.f,0.f}, a1 = {0.f,0.f,0.f,0.f};
        bf16x8 b0 = *(const bf16x8*)&cw2s[(nc * 32 + l16) * 40 + quad * 8];
        bf16x8 b1 = *(const bf16x8*)&cw2s[(nc * 32 + 16 + l16) * 40 + quad * 8];
        a0 = __builtin_amdgcn_mfma_f32_16x16x32_bf16(af, b0, a0, 0, 0, 0);
        a1 = __builtin_amdgcn_mfma_f32_16x16x32_bf16(af, b1, a1, 0, 0, 0);
        #pragma unroll
        for (int nn = 0; nn < 2; ++nn) {
            int o = nc * 32 + nn * 16 + l16;
            float cb = cb2s[o];
            const f32x4& aa = nn ? a1 : a0;
            #pragma unroll
            for (int r = 0; r < 4; ++r) {
                int pxl = wv * 16 + quad * 4 + r;
                wlT[pxl * 40 + nn * 16 + l16] = f2bf(aa[r] + cb);
            }
        }
        __syncthreads();
        // transposed coalesced flush: 32 o-rows x 32 px-pairs
        for (int p = 0; p < 4; ++p) {
            int idx = t + 256 * p;
            int r = idx >> 5, pw = idx & 31;
            u32 pk = (u32)wlT[(2 * pw) * 40 + r] | ((u32)wlT[(2 * pw + 1) * 40 + r] << 16);
            wlw[(((b * 288) + nc * 32 + r) * 4096 + hw0) / 2 + pw] = pk;
        }
        __syncthreads();
    }
}

// =====================================================================
// lconv_k: out[b][g*8+s][hw] = sum_k wloc[b][g*9+k][hw] * x3[zero-pad 3x3]
// =====================================================================
__global__ __launch_bounds__(256) void lconv_k(
    const u16* __restrict__ y, const u16* __restrict__ wloc,
    const u32* __restrict__ flagp, void* __restrict__ outv)
{
    __shared__ u16 x3s[8 * 34 * 64];   // [s][row(-1..32)][w]
    const int hf = blockIdx.x, g = blockIdx.y, b = blockIdx.z;
    const int h0 = hf * 32;
    const int t = threadIdx.x;
    const int isf32 = (int)*flagp;

    {   // stage x3 slab (zero-pad h boundary)
        const u32* yw = (const u32*)y;
        int s = t >> 5, l = t & 31;
        int ch = 64 + g * 8 + s;
        for (int q = 0; q < 34; ++q) {
            int hr = h0 + q - 1;
            u32 v = 0;
            if (hr >= 0 && hr < 64) v = yw[(((b * 320) + ch) * 4096 + hr * 64) / 2 + l];
            *(u32*)&x3s[(s * 34 + q) * 64 + l * 2] = v;
        }
    }
    __syncthreads();

    for (int q = 0; q < 8; ++q) {
        int px = t + 256 * q;
        int hl = px >> 6, w = px & 63;
        float wv9[9];
        #pragma unroll
        for (int k = 0; k < 9; ++k)
            wv9[k] = b2f(wloc[((b * 288) + g * 9 + k) * 4096 + h0 * 64 + px]);
        #pragma unroll
        for (int s = 0; s < 8; ++s) {
            float acc = 0.f;
            #pragma unroll
            for (int i3 = 0; i3 < 3; ++i3) {
                const u16* rowp = &x3s[(s * 34 + hl + i3) * 64];
                float a0 = (w > 0)  ? b2f(rowp[w - 1]) : 0.f;
                float a1 = b2f(rowp[w]);
                float a2 = (w < 63) ? b2f(rowp[w + 1]) : 0.f;
                acc += wv9[i3 * 3 + 0] * a0 + wv9[i3 * 3 + 1] * a1 + wv9[i3 * 3 + 2] * a2;
            }
            int oidx = ((b * 256) + g * 8 + s) * 4096 + h0 * 64 + px;
            if (isf32) ((float*)outv)[oidx] = acc;
            else       ((u16*)outv)[oidx] = f2bf(acc);
        }
    }
}

// =====================================================================
extern "C" void kernel_launch(void* const* d_in, const int* in_sizes, int n_in,
                              void* d_out, int out_size, void* d_ws, size_t ws_size,
                              hipStream_t stream) {
    (void)in_sizes; (void)n_in; (void)out_size; (void)ws_size;
    char* ws = (char*)d_ws;
    u16*   yb     = (u16*)  (ws + OFF_Y);
    u16*   Xt     = (u16*)  (ws + OFF_XT);
    u16*   wlocb  = (u16*)  (ws + OFF_WLOC);
    u16*   aAt    = (u16*)  (ws + OFF_AAT);
    u32*   flagws = (u32*)  (ws + FLAG_OFF);
    float* biasAll= (float*)(ws + BIAS_OFF);
    float* s1     = (float*)(ws + S1_OFF);
    float* t1     = (float*)(ws + T1_OFF);
    float* s2     = (float*)(ws + S2_OFF);
    float* t2     = (float*)(ws + T2_OFF);
    float* cb2f   = (float*)(ws + CB2_OFF);
    u16*   cw1c   = (u16*)  (ws + CW1_OFF);
    u16*   cw2c   = (u16*)  (ws + CW2_OFF);
    u16*   Wc     = (u16*)  (ws + WC_OFF);

    hipLaunchKernelGGL(setup_k, dim3(64), dim3(256), 0, stream,
                       d_in[1], d_in[2], d_in[3], d_in[4], d_in[5], d_in[6],
                       d_in[7], d_in[8], d_in[9], d_in[10], d_in[11],
                       d_in[12], d_in[13], d_in[14], d_in[15], d_in[16], d_in[17],
                       flagws, Wc, biasAll, s1, t1, cw1c, s2, t2, cw2c, cb2f);
    hipLaunchKernelGGL(transpose_k, dim3(64, 4, 8), dim3(256), 0, stream,
                       d_in[0], flagws, Xt);
    hipLaunchKernelGGL(conv_k, dim3(16, 5, 8), dim3(256), 0, stream,
                       Wc, Xt, biasAll, yb);
    hipLaunchKernelGGL(wgen1_k, dim3(64, 8), dim3(256), 0, stream,
                       yb, cw1c, s1, t1, s2, t2, aAt);
    hipLaunchKernelGGL(wgen2_k, dim3(64, 8), dim3(256), 0, stream,
                       aAt, cw2c, cb2f, wlocb);
    hipLaunchKernelGGL(lconv_k, dim3(2, 32, 8), dim3(256), 0, stream,
                       yb, wlocb, flagws, d_out);
}